// Round 7
// baseline (360.329 us; speedup 1.0000x reference)
//
#include <hip/hip_runtime.h>

#define BATCH 512
#define ZDIM 256

// ---------------------------------------------------------------- helpers

__device__ __forceinline__ float fast_exp2(float x) {
#if __has_builtin(__builtin_amdgcn_exp2f)
    return __builtin_amdgcn_exp2f(x);   // v_exp_f32 (2^x)
#else
    return exp2f(x);
#endif
}

__device__ __forceinline__ float wave_reduce_sum(float v) {
#pragma unroll
    for (int off = 32; off > 0; off >>= 1)
        v += __shfl_down(v, off, 64);
    return v;
}

__device__ __forceinline__ float wave_reduce_max(float v) {
#pragma unroll
    for (int off = 32; off > 0; off >>= 1)
        v = fmaxf(v, __shfl_down(v, off, 64));
    return v;
}

// block of 256 threads = 4 waves; result broadcast to all threads
__device__ __forceinline__ float block_sum256(float v, float* red) {
    float w = wave_reduce_sum(v);
    if ((threadIdx.x & 63) == 0) red[threadIdx.x >> 6] = w;
    __syncthreads();
    float r = red[0] + red[1] + red[2] + red[3];
    __syncthreads();
    return r;
}

// producer release: all block stores drained by __syncthreads (vmcnt(0)
// before s_barrier), then agent-scope RELEASE add (L2 writeback).
__device__ __forceinline__ void release_count(unsigned int* c) {
    __syncthreads();
    if (threadIdx.x == 0)
        __hip_atomic_fetch_add(c, 1u, __ATOMIC_RELEASE, __HIP_MEMORY_SCOPE_AGENT);
}

// consumer acquire: thread-0 spin with agent-scope ACQUIRE (cache inv),
// then barrier -> whole block sees producers' plain stores.
__device__ __forceinline__ void acquire_count(unsigned int* c, unsigned int tgt) {
    if (threadIdx.x == 0) {
        while (__hip_atomic_load(c, __ATOMIC_ACQUIRE, __HIP_MEMORY_SCOPE_AGENT) < tgt)
            __builtin_amdgcn_s_sleep(2);
    }
    __syncthreads();
}

// ---------------------------------------------------------------- mega kernel
// blocks [0,512)    : tables(j=b) -> tcnt -> wait tcnt=512 -> pm(pb=b)
//                     -> pcnt -> wait pcnt=1152 -> finalize(i=b)
// blocks [512,1024) : rec BCE (rb=b-512), no table dependency -> pcnt
// blocks [1024,1152): wait tcnt=512 -> smat(sb=b-1024) -> pcnt
__global__ __launch_bounds__(256, 5) void k_mega(
    const float4* __restrict__ d, const float4* __restrict__ r,
    const float* __restrict__ lat,
    const float* __restrict__ mu, const float* __restrict__ logvar,
    const int* __restrict__ dsz,
    float4* __restrict__ abc, float2* __restrict__ e2wT2,
    float* __restrict__ cj, float* __restrict__ dwrow,
    float* __restrict__ recpart, float* __restrict__ part,
    float* __restrict__ smat, float* __restrict__ tcpart,
    unsigned int* __restrict__ cnts, float* __restrict__ out) {
    __shared__ float ss[8 * ZDIM];
    __shared__ float red[4];
    int b = blockIdx.x, t = threadIdx.x;
    unsigned int* tcnt = cnts + 0;   // tables done
    unsigned int* pcnt = cnts + 1;   // producers (pm+rec+smat) done
    unsigned int* cnt3 = cnts + 2;   // finalize last-block

    if (b < 512) {
        // ---------------- phase A: tables row j = b ----------------
        {
            int j = b, k = t;
            float m = mu[j * ZDIM + k];
            float lv = logvar[j * ZDIM + k];
            float ev = __expf(lv);
            float e2n = -0.5f * ev;
            float lcn = -0.5f * (lv + 1.8378770664093453f);   // -0.5*(lv+LOG2PI)
            const float L2E = 1.4426950408889634f;
            float cpart = m * m * e2n + lcn;                  // natural scale
            abc[j * ZDIM + k] = make_float4(e2n * L2E, m * ev * L2E,
                                            cpart * L2E, 0.f);
            // paired-k transposed table: float2 slot (k>>1)*BATCH+j, half k&1
            e2wT2[(((k >> 1) * BATCH + j) << 1) + (k & 1)] =
                make_float2(e2n, m * ev);
            float csum = block_sum256(cpart, red);
            if (k == 0) cj[j] = csum;
            float dw = -0.5f * lv + 0.5f * __expf(lv + m * m) - 0.5f;
            float dsum = block_sum256(dw, red);
            if (k == 0) dwrow[j] = dsum;
        }
        release_count(tcnt);
        acquire_count(tcnt, 512u);
        // ---------------- phase B: pm partials, pb = b ----------------
        {
            int i0 = (b >> 3) * 8, j0 = (b & 7) * 64;
            float s[8], s2[8], a[8];
#pragma unroll
            for (int i = 0; i < 8; i++) {
                s[i] = lat[(i0 + i) * ZDIM + t];
                s2[i] = s[i] * s[i];
                a[i] = 0.f;
            }
            for (int j2 = 0; j2 < 16; j2++) {
                int j = j0 + j2 * 4;
                float4 q0 = abc[(j + 0) * ZDIM + t];
                float4 q1 = abc[(j + 1) * ZDIM + t];
                float4 q2 = abc[(j + 2) * ZDIM + t];
                float4 q3 = abc[(j + 3) * ZDIM + t];
#pragma unroll
                for (int i = 0; i < 8; i++) {
                    a[i] += fast_exp2(fmaf(s2[i], q0.x, fmaf(s[i], q0.y, q0.z)));
                    a[i] += fast_exp2(fmaf(s2[i], q1.x, fmaf(s[i], q1.y, q1.z)));
                    a[i] += fast_exp2(fmaf(s2[i], q2.x, fmaf(s[i], q2.y, q2.z)));
                    a[i] += fast_exp2(fmaf(s2[i], q3.x, fmaf(s[i], q3.y, q3.z)));
                }
            }
#pragma unroll
            for (int i = 0; i < 8; i++)
                part[((b & 7) * BATCH + i0 + i) * ZDIM + t] = a[i];
        }
        release_count(pcnt);
        acquire_count(pcnt, 1152u);
        // ---------------- phase C: finalize row i = b ----------------
        {
            int i = b;
            float s = 0.f;
#pragma unroll
            for (int jc = 0; jc < 8; jc++)
                s += part[(jc * BATCH + i) * ZDIM + t];
            float prod_i = block_sum256(__logf(s), red);
            float v1 = smat[i * BATCH + t];
            float v2 = smat[i * BATCH + 256 + t];
            float m = wave_reduce_max(fmaxf(v1, v2));
            if ((t & 63) == 0) red[t >> 6] = m;
            __syncthreads();
            m = fmaxf(fmaxf(red[0], red[1]), fmaxf(red[2], red[3]));
            __syncthreads();
            float e = __expf(v1 - m) + __expf(v2 - m);
            float sum = block_sum256(e, red);
            __shared__ bool amLast;
            if (t == 0) {
                float log_norm = __logf(512.f) + __logf((float)dsz[0]);
                float logqz = m + __logf(sum) - log_norm;
                float pm = prod_i - 256.f * log_norm;   // Z * log_norm
                __hip_atomic_store(&tcpart[i], logqz - pm, __ATOMIC_RELAXED,
                                   __HIP_MEMORY_SCOPE_AGENT);
                unsigned int old = __hip_atomic_fetch_add(
                    cnt3, 1u, __ATOMIC_ACQ_REL, __HIP_MEMORY_SCOPE_AGENT);
                amLast = (old == BATCH - 1);
            }
            __syncthreads();
            if (amLast) {
                float acc = 0.f;
                float tc1 = __hip_atomic_load(&tcpart[t], __ATOMIC_RELAXED,
                                              __HIP_MEMORY_SCOPE_AGENT);
                float tc2 = __hip_atomic_load(&tcpart[t + 256], __ATOMIC_RELAXED,
                                              __HIP_MEMORY_SCOPE_AGENT);
                acc += tc1 + tc2;
                acc += dwrow[t] + dwrow[t + 256];
                acc -= recpart[t] + recpart[t + 256];
                float tot = block_sum256(acc, red);
                if (t == 0) out[0] = tot * (1.f / 512.f);
            }
        }
    } else if (b < 1024) {
        // ---------------- rec BCE, rb = b-512 ----------------
        int rb = b - 512;
        float s = 0.f;
        int base = rb * 256 + t;
#pragma unroll 4
        for (int it = 0; it < 12; ++it) {
            int idx = base + it * 131072;
            float4 dv = d[idx];
            float4 rv = r[idx];
            s += dv.x * __logf(rv.x) + (1.f - dv.x) * __logf(1.f - rv.x);
            s += dv.y * __logf(rv.y) + (1.f - dv.y) * __logf(1.f - rv.y);
            s += dv.z * __logf(rv.z) + (1.f - dv.z) * __logf(1.f - rv.z);
            s += dv.w * __logf(rv.w) + (1.f - dv.w) * __logf(1.f - rv.w);
        }
        float tot = block_sum256(s, red);
        if (t == 0) recpart[rb] = tot;
        release_count(pcnt);
    } else {
        // ---------------- smat, sb = b-1024 ----------------
        acquire_count(tcnt, 512u);
        int sb = b - 1024;
        int i0 = (sb >> 1) * 8;
        int j = (sb & 1) * 256 + t;
#pragma unroll
        for (int li = 0; li < 8; li++)
            ss[t * 8 + li] = lat[(i0 + li) * ZDIM + t];
        __syncthreads();
        float acc[8];
#pragma unroll
        for (int i = 0; i < 8; i++) acc[i] = 0.f;
        const float4* e2w4 = (const float4*)e2wT2;
#pragma unroll 4
        for (int k2 = 0; k2 < ZDIM / 2; k2++) {
            float4 ew = e2w4[k2 * BATCH + j];           // e2,w for k=2k2,2k2+1
            const float4* sp = (const float4*)(ss + (2 * k2) * 8);
            float4 sa = sp[0], sb2 = sp[1];             // k even: i0..7
            float4 sc = sp[2], sd = sp[3];              // k odd : i0..7
            acc[0] = fmaf(sa.x, fmaf(sa.x, ew.x, ew.y), acc[0]);
            acc[1] = fmaf(sa.y, fmaf(sa.y, ew.x, ew.y), acc[1]);
            acc[2] = fmaf(sa.z, fmaf(sa.z, ew.x, ew.y), acc[2]);
            acc[3] = fmaf(sa.w, fmaf(sa.w, ew.x, ew.y), acc[3]);
            acc[4] = fmaf(sb2.x, fmaf(sb2.x, ew.x, ew.y), acc[4]);
            acc[5] = fmaf(sb2.y, fmaf(sb2.y, ew.x, ew.y), acc[5]);
            acc[6] = fmaf(sb2.z, fmaf(sb2.z, ew.x, ew.y), acc[6]);
            acc[7] = fmaf(sb2.w, fmaf(sb2.w, ew.x, ew.y), acc[7]);
            acc[0] = fmaf(sc.x, fmaf(sc.x, ew.z, ew.w), acc[0]);
            acc[1] = fmaf(sc.y, fmaf(sc.y, ew.z, ew.w), acc[1]);
            acc[2] = fmaf(sc.z, fmaf(sc.z, ew.z, ew.w), acc[2]);
            acc[3] = fmaf(sc.w, fmaf(sc.w, ew.z, ew.w), acc[3]);
            acc[4] = fmaf(sd.x, fmaf(sd.x, ew.z, ew.w), acc[4]);
            acc[5] = fmaf(sd.y, fmaf(sd.y, ew.z, ew.w), acc[5]);
            acc[6] = fmaf(sd.z, fmaf(sd.z, ew.z, ew.w), acc[6]);
            acc[7] = fmaf(sd.w, fmaf(sd.w, ew.z, ew.w), acc[7]);
        }
        float c = cj[j];
#pragma unroll
        for (int i = 0; i < 8; i++)
            smat[(i0 + i) * BATCH + j] = acc[i] + c;
        release_count(pcnt);
    }
}

// ---------------------------------------------------------------- launch

extern "C" void kernel_launch(void* const* d_in, const int* in_sizes, int n_in,
                              void* d_out, int out_size, void* d_ws, size_t ws_size,
                              hipStream_t stream) {
    const float* data   = (const float*)d_in[0];
    const float* recon  = (const float*)d_in[1];
    const float* lat    = (const float*)d_in[2];
    const float* mu     = (const float*)d_in[3];
    const float* logvar = (const float*)d_in[4];
    const int*   dsz    = (const int*)d_in[5];
    float* out = (float*)d_out;

    // workspace layout (float offsets)
    float*  ws      = (float*)d_ws;
    unsigned int* cnts = (unsigned int*)ws;         // [0]=tcnt [1]=pcnt [2]=cnt3
    float*  recpart = ws + 64;                      // 512
    float*  dwrow   = recpart + 512;                // 512
    float*  tcpart  = dwrow + 512;                  // 512
    float*  cj      = tcpart + 512;                 // 512
    float4* abc     = (float4*)(ws + 4096);         // 131072 float4 (2 MB)
    float*  e2wT2   = ws + 4096 + 524288;           // 131072 float2 (1 MB)
    float*  part    = ws + 4096 + 786432;           // 8*131072 = 1048576
    float*  smat    = part + 1048576;               // 262144

    hipMemsetAsync(cnts, 0, 256, stream);           // zero sync counters only

    k_mega<<<1152, 256, 0, stream>>>((const float4*)data, (const float4*)recon,
                                     lat, mu, logvar, dsz,
                                     abc, (float2*)e2wT2, cj, dwrow,
                                     recpart, part, smat, tcpart, cnts, out);
}

// Round 8
// 120.346 us; speedup vs baseline: 2.9941x; 2.9941x over previous
//
#include <hip/hip_runtime.h>

#define BATCH 512
#define ZDIM 256

// ---------------------------------------------------------------- helpers

__device__ __forceinline__ float fast_exp2(float x) {
#if __has_builtin(__builtin_amdgcn_exp2f)
    return __builtin_amdgcn_exp2f(x);   // v_exp_f32 (2^x)
#else
    return exp2f(x);
#endif
}

__device__ __forceinline__ float wave_reduce_sum(float v) {
#pragma unroll
    for (int off = 32; off > 0; off >>= 1)
        v += __shfl_down(v, off, 64);
    return v;
}

__device__ __forceinline__ float wave_reduce_max(float v) {
#pragma unroll
    for (int off = 32; off > 0; off >>= 1)
        v = fmaxf(v, __shfl_down(v, off, 64));
    return v;
}

// block of 256 threads = 4 waves; result broadcast to all threads
__device__ __forceinline__ float block_sum256(float v, float* red) {
    float w = wave_reduce_sum(v);
    if ((threadIdx.x & 63) == 0) red[threadIdx.x >> 6] = w;
    __syncthreads();
    float r = red[0] + red[1] + red[2] + red[3];
    __syncthreads();
    return r;
}

// ---------------------------------------------------------------- kernels

// K1 (512 blocks): per-(j,k) tables + cj + dwrow[j]; block 0 zeroes cnt.
// NOTE (R7 lesson): intra-kernel spin sync on agent-scope acquire loads
// costs ~300us on CDNA4 (per-iteration cache invalidation). Kernel-boundary
// drain (~3us) is the cheap dependency mechanism — keep 3 nodes.
__global__ __launch_bounds__(256) void k_tables(
    const float* __restrict__ mu, const float* __restrict__ logvar,
    float4* __restrict__ abc, float2* __restrict__ e2wT2,
    float* __restrict__ cj, float* __restrict__ dwrow,
    unsigned int* __restrict__ cnt) {
    __shared__ float red[4];
    int j = blockIdx.x, k = threadIdx.x;
    if (j == 0 && k == 0) cnt[0] = 0u;   // init last-block counter for K3
    float m = mu[j * ZDIM + k];
    float lv = logvar[j * ZDIM + k];
    float ev = __expf(lv);
    float e2n = -0.5f * ev;
    float lcn = -0.5f * (lv + 1.8378770664093453f);   // -0.5*(lv + LOG2PI)
    const float L2E = 1.4426950408889634f;
    float cpart = m * m * e2n + lcn;                  // natural scale
    abc[j * ZDIM + k] = make_float4(e2n * L2E, m * ev * L2E, cpart * L2E, 0.f);
    // paired-k transposed table: float2 slot (k>>1)*BATCH + j, half k&1
    e2wT2[(((k >> 1) * BATCH + j) << 1) + (k & 1)] = make_float2(e2n, m * ev);
    float csum = block_sum256(cpart, red);
    if (k == 0) cj[j] = csum;
    float dw = -0.5f * lv + 0.5f * __expf(lv + m * m) - 0.5f;
    float dsum = block_sum256(dw, red);
    if (k == 0) dwrow[j] = dsum;
}

// K2 (1152 blocks): [0,128) smat; [128,640) pm partials; [640,1152) rec BCE.
// Three-way co-residency: HBM-streamer (rec) + trans-bound (pm) + FMA-bound
// (smat) overlap across CUs — splitting any of these out regressed (R4/R6).
__global__ __launch_bounds__(256) void k_bulk(
    const float4* __restrict__ d, const float4* __restrict__ r,
    const float* __restrict__ lat, const float4* __restrict__ abc,
    float* __restrict__ part,
    const float4* __restrict__ e2wT2, const float* __restrict__ cj,
    float* __restrict__ smat, float* __restrict__ recpart) {
    __shared__ float ss[8 * ZDIM];   // smat: lat tile transposed; else: red
    int b = blockIdx.x, t = threadIdx.x;
    if (b < 128) {
        // S matrix: 8 i's per block, thread = j within 256-chunk
        int i0 = (b >> 1) * 8;
        int j = (b & 1) * 256 + t;
        // stage transposed: ss[k*8 + li] ; thread t stages column k = t
#pragma unroll
        for (int li = 0; li < 8; li++)
            ss[t * 8 + li] = lat[(i0 + li) * ZDIM + t];
        __syncthreads();
        float acc[8];
#pragma unroll
        for (int i = 0; i < 8; i++) acc[i] = 0.f;
#pragma unroll 4
        for (int k2 = 0; k2 < ZDIM / 2; k2++) {
            float4 ew = e2wT2[k2 * BATCH + j];          // e2,w for k=2k2,2k2+1
            const float4* sp = (const float4*)(ss + (2 * k2) * 8);
            float4 sa = sp[0], sb = sp[1];              // k even: i0..7
            float4 sc = sp[2], sd = sp[3];              // k odd : i0..7
            acc[0] = fmaf(sa.x, fmaf(sa.x, ew.x, ew.y), acc[0]);
            acc[1] = fmaf(sa.y, fmaf(sa.y, ew.x, ew.y), acc[1]);
            acc[2] = fmaf(sa.z, fmaf(sa.z, ew.x, ew.y), acc[2]);
            acc[3] = fmaf(sa.w, fmaf(sa.w, ew.x, ew.y), acc[3]);
            acc[4] = fmaf(sb.x, fmaf(sb.x, ew.x, ew.y), acc[4]);
            acc[5] = fmaf(sb.y, fmaf(sb.y, ew.x, ew.y), acc[5]);
            acc[6] = fmaf(sb.z, fmaf(sb.z, ew.x, ew.y), acc[6]);
            acc[7] = fmaf(sb.w, fmaf(sb.w, ew.x, ew.y), acc[7]);
            acc[0] = fmaf(sc.x, fmaf(sc.x, ew.z, ew.w), acc[0]);
            acc[1] = fmaf(sc.y, fmaf(sc.y, ew.z, ew.w), acc[1]);
            acc[2] = fmaf(sc.z, fmaf(sc.z, ew.z, ew.w), acc[2]);
            acc[3] = fmaf(sc.w, fmaf(sc.w, ew.z, ew.w), acc[3]);
            acc[4] = fmaf(sd.x, fmaf(sd.x, ew.z, ew.w), acc[4]);
            acc[5] = fmaf(sd.y, fmaf(sd.y, ew.z, ew.w), acc[5]);
            acc[6] = fmaf(sd.z, fmaf(sd.z, ew.z, ew.w), acc[6]);
            acc[7] = fmaf(sd.w, fmaf(sd.w, ew.z, ew.w), acc[7]);
        }
        float c = cj[j];
#pragma unroll
        for (int i = 0; i < 8; i++)
            smat[(i0 + i) * BATCH + j] = acc[i] + c;
    } else if (b < 640) {
        // pm partials: 8 i's x 64 j's per block; thread = k; 8 j's per wait
        int pb = b - 128;
        int i0 = (pb >> 3) * 8, j0 = (pb & 7) * 64;
        float s[8], s2[8], a[8];
#pragma unroll
        for (int i = 0; i < 8; i++) {
            s[i] = lat[(i0 + i) * ZDIM + t];
            s2[i] = s[i] * s[i];
            a[i] = 0.f;
        }
        for (int j8 = 0; j8 < 8; j8++) {
            int j = j0 + j8 * 8;
            float4 q[8];
#pragma unroll
            for (int u = 0; u < 8; u++)
                q[u] = abc[(j + u) * ZDIM + t];
#pragma unroll
            for (int u = 0; u < 8; u++) {
#pragma unroll
                for (int i = 0; i < 8; i++)
                    a[i] += fast_exp2(fmaf(s2[i], q[u].x,
                                           fmaf(s[i], q[u].y, q[u].z)));
            }
        }
#pragma unroll
        for (int i = 0; i < 8; i++)
            part[((pb & 7) * BATCH + i0 + i) * ZDIM + t] = a[i];
    } else {
        // BCE: n4 = 1572864 = 131072 threads * 12 iters
        int rb = b - 640;
        float s = 0.f;
        int base = rb * 256 + t;
#pragma unroll 4
        for (int it = 0; it < 12; ++it) {
            int idx = base + it * 131072;
            float4 dv = d[idx];
            float4 rv = r[idx];
            s += dv.x * __logf(rv.x) + (1.f - dv.x) * __logf(1.f - rv.x);
            s += dv.y * __logf(rv.y) + (1.f - dv.y) * __logf(1.f - rv.y);
            s += dv.z * __logf(rv.z) + (1.f - dv.z) * __logf(1.f - rv.z);
            s += dv.w * __logf(rv.w) + (1.f - dv.w) * __logf(1.f - rv.w);
        }
        float tot = block_sum256(s, ss);
        if (t == 0) recpart[rb] = tot;
    }
}

// K3 (512 blocks): block i = merge pm partials -> prod_i, lse over S row i,
// tc_i -> tcpart[i] (agent-scope store); last block sums everything -> out.
__global__ __launch_bounds__(256) void k_finalize(
    const float* __restrict__ part, const float* __restrict__ smat,
    const int* __restrict__ dsz, const float* __restrict__ recpart,
    const float* __restrict__ dwrow, float* __restrict__ tcpart,
    unsigned int* __restrict__ cnt, float* __restrict__ out) {
    __shared__ float red[4];
    int i = blockIdx.x, t = threadIdx.x;
    // merge j-chunk partials -> prod_i = sum_k ln(sum_j exp(v))
    float s = 0.f;
#pragma unroll
    for (int jc = 0; jc < 8; jc++)
        s += part[(jc * BATCH + i) * ZDIM + t];
    float prod_i = block_sum256(__logf(s), red);
    // lse over S row i (max-shifted; S ~ -360)
    float v1 = smat[i * BATCH + t];
    float v2 = smat[i * BATCH + 256 + t];
    float m = wave_reduce_max(fmaxf(v1, v2));
    if ((t & 63) == 0) red[t >> 6] = m;
    __syncthreads();
    m = fmaxf(fmaxf(red[0], red[1]), fmaxf(red[2], red[3]));
    __syncthreads();
    float e = __expf(v1 - m) + __expf(v2 - m);
    float sum = block_sum256(e, red);
    __shared__ bool amLast;
    if (t == 0) {
        float log_norm = __logf(512.f) + __logf((float)dsz[0]);
        float logqz = m + __logf(sum) - log_norm;
        float pm = prod_i - 256.f * log_norm;   // Z * log_norm
        __hip_atomic_store(&tcpart[i], logqz - pm, __ATOMIC_RELAXED,
                           __HIP_MEMORY_SCOPE_AGENT);
        unsigned int old = __hip_atomic_fetch_add(cnt, 1u, __ATOMIC_ACQ_REL,
                                                  __HIP_MEMORY_SCOPE_AGENT);
        amLast = (old == BATCH - 1);
    }
    __syncthreads();
    if (amLast) {
        // recpart/dwrow are cross-kernel (visible at dispatch acquire);
        // tcpart is intra-kernel -> agent-scope loads to bypass stale L2.
        float acc = 0.f;
        float tc1 = __hip_atomic_load(&tcpart[t], __ATOMIC_RELAXED,
                                      __HIP_MEMORY_SCOPE_AGENT);
        float tc2 = __hip_atomic_load(&tcpart[t + 256], __ATOMIC_RELAXED,
                                      __HIP_MEMORY_SCOPE_AGENT);
        acc += tc1 + tc2;
        acc += dwrow[t] + dwrow[t + 256];
        acc -= recpart[t] + recpart[t + 256];
        float tot = block_sum256(acc, red);
        if (t == 0) out[0] = tot * (1.f / 512.f);
    }
}

// ---------------------------------------------------------------- launch

extern "C" void kernel_launch(void* const* d_in, const int* in_sizes, int n_in,
                              void* d_out, int out_size, void* d_ws, size_t ws_size,
                              hipStream_t stream) {
    const float* data   = (const float*)d_in[0];
    const float* recon  = (const float*)d_in[1];
    const float* lat    = (const float*)d_in[2];
    const float* mu     = (const float*)d_in[3];
    const float* logvar = (const float*)d_in[4];
    const int*   dsz    = (const int*)d_in[5];
    float* out = (float*)d_out;

    // workspace layout (float offsets) — every slot fully overwritten each call
    float*  ws      = (float*)d_ws;
    unsigned int* cnt = (unsigned int*)ws;          // [0] (zeroed by K1)
    float*  recpart = ws + 64;                      // 512
    float*  dwrow   = recpart + 512;                // 512
    float*  tcpart  = dwrow + 512;                  // 512
    float*  cj      = tcpart + 512;                 // 512
    float4* abc     = (float4*)(ws + 4096);         // 131072 float4 (2 MB)
    float*  e2wT2   = ws + 4096 + 524288;           // 131072 float2 (1 MB)
    float*  part    = ws + 4096 + 786432;           // 8*131072 = 1048576
    float*  smat    = part + 1048576;               // 262144

    k_tables<<<512, 256, 0, stream>>>(mu, logvar, abc, (float2*)e2wT2,
                                      cj, dwrow, cnt);
    k_bulk<<<1152, 256, 0, stream>>>((const float4*)data, (const float4*)recon,
                                     lat, abc, part, (const float4*)e2wT2,
                                     cj, smat, recpart);
    k_finalize<<<512, 256, 0, stream>>>(part, smat, dsz, recpart, dwrow,
                                        tcpart, cnt, out);
}

// Round 9
// 117.793 us; speedup vs baseline: 3.0590x; 1.0217x over previous
//
#include <hip/hip_runtime.h>

#define BATCH 512
#define ZDIM 256

// ---------------------------------------------------------------- helpers

__device__ __forceinline__ float fast_exp2(float x) {
#if __has_builtin(__builtin_amdgcn_exp2f)
    return __builtin_amdgcn_exp2f(x);   // v_exp_f32 (2^x)
#else
    return exp2f(x);
#endif
}

__device__ __forceinline__ float wave_reduce_sum(float v) {
#pragma unroll
    for (int off = 32; off > 0; off >>= 1)
        v += __shfl_down(v, off, 64);
    return v;
}

__device__ __forceinline__ float wave_reduce_max(float v) {
#pragma unroll
    for (int off = 32; off > 0; off >>= 1)
        v = fmaxf(v, __shfl_down(v, off, 64));
    return v;
}

// block of 256 threads = 4 waves; result broadcast to all threads
__device__ __forceinline__ float block_sum256(float v, float* red) {
    float w = wave_reduce_sum(v);
    if ((threadIdx.x & 63) == 0) red[threadIdx.x >> 6] = w;
    __syncthreads();
    float r = red[0] + red[1] + red[2] + red[3];
    __syncthreads();
    return r;
}

// ---------------------------------------------------------------- kernels

// K1 (512 blocks): per-(j,k) tables + cj + dwrow[j]; block 0 zeroes cnt.
// NOTE (R7 lesson): intra-kernel spin sync on agent-scope acquire loads
// costs ~300us on CDNA4 (per-iteration cache invalidation). Kernel-boundary
// drain (~3us) is the cheap dependency mechanism — keep 3 nodes.
__global__ __launch_bounds__(256) void k_tables(
    const float* __restrict__ mu, const float* __restrict__ logvar,
    float4* __restrict__ abc, float2* __restrict__ e2wT2,
    float* __restrict__ cj, float* __restrict__ dwrow,
    unsigned int* __restrict__ cnt) {
    __shared__ float red[4];
    int j = blockIdx.x, k = threadIdx.x;
    if (j == 0 && k == 0) cnt[0] = 0u;   // init last-block counter for K3
    float m = mu[j * ZDIM + k];
    float lv = logvar[j * ZDIM + k];
    float ev = __expf(lv);
    float e2n = -0.5f * ev;
    float lcn = -0.5f * (lv + 1.8378770664093453f);   // -0.5*(lv + LOG2PI)
    const float L2E = 1.4426950408889634f;
    float cpart = m * m * e2n + lcn;                  // natural scale
    abc[j * ZDIM + k] = make_float4(e2n * L2E, m * ev * L2E, cpart * L2E, 0.f);
    // paired-k transposed table: float2 slot (k>>1)*BATCH + j, half k&1
    e2wT2[(((k >> 1) * BATCH + j) << 1) + (k & 1)] = make_float2(e2n, m * ev);
    float csum = block_sum256(cpart, red);
    if (k == 0) cj[j] = csum;
    float dw = -0.5f * lv + 0.5f * __expf(lv + m * m) - 0.5f;
    float dsum = block_sum256(dw, red);
    if (k == 0) dwrow[j] = dsum;
}

// K2 (1152 blocks): [0,128) smat; [128,640) pm partials; [640,1152) rec BCE.
// Three-way co-residency: HBM/L3-streamer (rec) + trans-bound (pm) +
// FMA-bound (smat) overlap across CUs — splitting any out regressed (R4/R6).
// pm: TI=16 i's x 32 j's per block (512 blocks) — halves abc re-read traffic
// vs TI=8/64j while keeping block-level latency hiding (R4 lesson).
__global__ __launch_bounds__(256) void k_bulk(
    const float4* __restrict__ d, const float4* __restrict__ r,
    const float* __restrict__ lat, const float4* __restrict__ abc,
    float* __restrict__ part,
    const float4* __restrict__ e2wT2, const float* __restrict__ cj,
    float* __restrict__ smat, float* __restrict__ recpart) {
    __shared__ float ss[8 * ZDIM];   // smat: lat tile transposed; else: red
    int b = blockIdx.x, t = threadIdx.x;
    if (b < 128) {
        // S matrix: 8 i's per block, thread = j within 256-chunk
        int i0 = (b >> 1) * 8;
        int j = (b & 1) * 256 + t;
        // stage transposed: ss[k*8 + li] ; thread t stages column k = t
#pragma unroll
        for (int li = 0; li < 8; li++)
            ss[t * 8 + li] = lat[(i0 + li) * ZDIM + t];
        __syncthreads();
        float acc[8];
#pragma unroll
        for (int i = 0; i < 8; i++) acc[i] = 0.f;
#pragma unroll 4
        for (int k2 = 0; k2 < ZDIM / 2; k2++) {
            float4 ew = e2wT2[k2 * BATCH + j];          // e2,w for k=2k2,2k2+1
            const float4* sp = (const float4*)(ss + (2 * k2) * 8);
            float4 sa = sp[0], sb = sp[1];              // k even: i0..7
            float4 sc = sp[2], sd = sp[3];              // k odd : i0..7
            acc[0] = fmaf(sa.x, fmaf(sa.x, ew.x, ew.y), acc[0]);
            acc[1] = fmaf(sa.y, fmaf(sa.y, ew.x, ew.y), acc[1]);
            acc[2] = fmaf(sa.z, fmaf(sa.z, ew.x, ew.y), acc[2]);
            acc[3] = fmaf(sa.w, fmaf(sa.w, ew.x, ew.y), acc[3]);
            acc[4] = fmaf(sb.x, fmaf(sb.x, ew.x, ew.y), acc[4]);
            acc[5] = fmaf(sb.y, fmaf(sb.y, ew.x, ew.y), acc[5]);
            acc[6] = fmaf(sb.z, fmaf(sb.z, ew.x, ew.y), acc[6]);
            acc[7] = fmaf(sb.w, fmaf(sb.w, ew.x, ew.y), acc[7]);
            acc[0] = fmaf(sc.x, fmaf(sc.x, ew.z, ew.w), acc[0]);
            acc[1] = fmaf(sc.y, fmaf(sc.y, ew.z, ew.w), acc[1]);
            acc[2] = fmaf(sc.z, fmaf(sc.z, ew.z, ew.w), acc[2]);
            acc[3] = fmaf(sc.w, fmaf(sc.w, ew.z, ew.w), acc[3]);
            acc[4] = fmaf(sd.x, fmaf(sd.x, ew.z, ew.w), acc[4]);
            acc[5] = fmaf(sd.y, fmaf(sd.y, ew.z, ew.w), acc[5]);
            acc[6] = fmaf(sd.z, fmaf(sd.z, ew.z, ew.w), acc[6]);
            acc[7] = fmaf(sd.w, fmaf(sd.w, ew.z, ew.w), acc[7]);
        }
        float c = cj[j];
#pragma unroll
        for (int i = 0; i < 8; i++)
            smat[(i0 + i) * BATCH + j] = acc[i] + c;
    } else if (b < 640) {
        // pm partials: 16 i's x 32 j's per block; thread = k; 4 j's per wait
        int pb = b - 128;
        int i0 = (pb >> 4) * 16, j0 = (pb & 15) * 32;
        float s[16], s2[16], a[16];
#pragma unroll
        for (int i = 0; i < 16; i++) {
            s[i] = lat[(i0 + i) * ZDIM + t];
            s2[i] = s[i] * s[i];
            a[i] = 0.f;
        }
        for (int j4 = 0; j4 < 8; j4++) {
            int j = j0 + j4 * 4;
            float4 q0 = abc[(j + 0) * ZDIM + t];
            float4 q1 = abc[(j + 1) * ZDIM + t];
            float4 q2 = abc[(j + 2) * ZDIM + t];
            float4 q3 = abc[(j + 3) * ZDIM + t];
#pragma unroll
            for (int i = 0; i < 16; i++) {
                a[i] += fast_exp2(fmaf(s2[i], q0.x, fmaf(s[i], q0.y, q0.z)));
                a[i] += fast_exp2(fmaf(s2[i], q1.x, fmaf(s[i], q1.y, q1.z)));
                a[i] += fast_exp2(fmaf(s2[i], q2.x, fmaf(s[i], q2.y, q2.z)));
                a[i] += fast_exp2(fmaf(s2[i], q3.x, fmaf(s[i], q3.y, q3.z)));
            }
        }
#pragma unroll
        for (int i = 0; i < 16; i++)
            part[((pb & 15) * BATCH + i0 + i) * ZDIM + t] = a[i];
    } else {
        // BCE: n4 = 1572864 = 131072 threads * 12 iters
        int rb = b - 640;
        float s = 0.f;
        int base = rb * 256 + t;
#pragma unroll 4
        for (int it = 0; it < 12; ++it) {
            int idx = base + it * 131072;
            float4 dv = d[idx];
            float4 rv = r[idx];
            s += dv.x * __logf(rv.x) + (1.f - dv.x) * __logf(1.f - rv.x);
            s += dv.y * __logf(rv.y) + (1.f - dv.y) * __logf(1.f - rv.y);
            s += dv.z * __logf(rv.z) + (1.f - dv.z) * __logf(1.f - rv.z);
            s += dv.w * __logf(rv.w) + (1.f - dv.w) * __logf(1.f - rv.w);
        }
        float tot = block_sum256(s, ss);
        if (t == 0) recpart[rb] = tot;
    }
}

// K3 (512 blocks): block i = merge pm partials -> prod_i, lse over S row i,
// tc_i -> tcpart[i] (agent-scope store); last block sums everything -> out.
__global__ __launch_bounds__(256) void k_finalize(
    const float* __restrict__ part, const float* __restrict__ smat,
    const int* __restrict__ dsz, const float* __restrict__ recpart,
    const float* __restrict__ dwrow, float* __restrict__ tcpart,
    unsigned int* __restrict__ cnt, float* __restrict__ out) {
    __shared__ float red[4];
    int i = blockIdx.x, t = threadIdx.x;
    // merge j-chunk partials -> prod_i = sum_k ln(sum_j exp(v))
    float s = 0.f;
#pragma unroll
    for (int jc = 0; jc < 16; jc++)
        s += part[(jc * BATCH + i) * ZDIM + t];
    float prod_i = block_sum256(__logf(s), red);
    // lse over S row i (max-shifted; S ~ -360)
    float v1 = smat[i * BATCH + t];
    float v2 = smat[i * BATCH + 256 + t];
    float m = wave_reduce_max(fmaxf(v1, v2));
    if ((t & 63) == 0) red[t >> 6] = m;
    __syncthreads();
    m = fmaxf(fmaxf(red[0], red[1]), fmaxf(red[2], red[3]));
    __syncthreads();
    float e = __expf(v1 - m) + __expf(v2 - m);
    float sum = block_sum256(e, red);
    __shared__ bool amLast;
    if (t == 0) {
        float log_norm = __logf(512.f) + __logf((float)dsz[0]);
        float logqz = m + __logf(sum) - log_norm;
        float pm = prod_i - 256.f * log_norm;   // Z * log_norm
        __hip_atomic_store(&tcpart[i], logqz - pm, __ATOMIC_RELAXED,
                           __HIP_MEMORY_SCOPE_AGENT);
        unsigned int old = __hip_atomic_fetch_add(cnt, 1u, __ATOMIC_ACQ_REL,
                                                  __HIP_MEMORY_SCOPE_AGENT);
        amLast = (old == BATCH - 1);
    }
    __syncthreads();
    if (amLast) {
        // recpart/dwrow are cross-kernel (visible at dispatch acquire);
        // tcpart is intra-kernel -> agent-scope loads to bypass stale L2.
        float acc = 0.f;
        float tc1 = __hip_atomic_load(&tcpart[t], __ATOMIC_RELAXED,
                                      __HIP_MEMORY_SCOPE_AGENT);
        float tc2 = __hip_atomic_load(&tcpart[t + 256], __ATOMIC_RELAXED,
                                      __HIP_MEMORY_SCOPE_AGENT);
        acc += tc1 + tc2;
        acc += dwrow[t] + dwrow[t + 256];
        acc -= recpart[t] + recpart[t + 256];
        float tot = block_sum256(acc, red);
        if (t == 0) out[0] = tot * (1.f / 512.f);
    }
}

// ---------------------------------------------------------------- launch

extern "C" void kernel_launch(void* const* d_in, const int* in_sizes, int n_in,
                              void* d_out, int out_size, void* d_ws, size_t ws_size,
                              hipStream_t stream) {
    const float* data   = (const float*)d_in[0];
    const float* recon  = (const float*)d_in[1];
    const float* lat    = (const float*)d_in[2];
    const float* mu     = (const float*)d_in[3];
    const float* logvar = (const float*)d_in[4];
    const int*   dsz    = (const int*)d_in[5];
    float* out = (float*)d_out;

    // workspace layout (float offsets) — every slot fully overwritten each call
    float*  ws      = (float*)d_ws;
    unsigned int* cnt = (unsigned int*)ws;          // [0] (zeroed by K1)
    float*  recpart = ws + 64;                      // 512
    float*  dwrow   = recpart + 512;                // 512
    float*  tcpart  = dwrow + 512;                  // 512
    float*  cj      = tcpart + 512;                 // 512
    float4* abc     = (float4*)(ws + 4096);         // 131072 float4 (2 MB)
    float*  e2wT2   = ws + 4096 + 524288;           // 131072 float2 (1 MB)
    float*  part    = ws + 4096 + 786432;           // 16*131072 = 2097152
    float*  smat    = part + 2097152;               // 262144

    k_tables<<<512, 256, 0, stream>>>(mu, logvar, abc, (float2*)e2wT2,
                                      cj, dwrow, cnt);
    k_bulk<<<1152, 256, 0, stream>>>((const float4*)data, (const float4*)recon,
                                     lat, abc, part, (const float4*)e2wT2,
                                     cj, smat, recpart);
    k_finalize<<<512, 256, 0, stream>>>(part, smat, dsz, recpart, dwrow,
                                        tcpart, cnt, out);
}